// Round 1
// baseline (3871.793 us; speedup 1.0000x reference)
//
#include <hip/hip_runtime.h>

#define VSZ 32000
#define TT 1024
#define LL 1024

typedef float f32x4 __attribute__((ext_vector_type(4)));

// ---------- fast activations (f32, ~2ulp; gates are saturated so plenty) ----------
__device__ __forceinline__ float fast_sigmoid(float x){
  return __builtin_amdgcn_rcpf(1.0f + __expf(-x));
}
__device__ __forceinline__ float fast_tanh(float x){
  float e = __expf(2.0f*x);
  return 1.0f - 2.0f*__builtin_amdgcn_rcpf(e + 1.0f);
}

// ---------- 15-lane GRU: lane g*5+i computes gate (g,i); s kept uniform in all lanes ----------
__device__ __forceinline__ void load_gru_w(const float* __restrict__ W,
                                           const float* __restrict__ U,
                                           const float* __restrict__ b,
                                           int lane, float Wr[5], float U1r[5], float U2r[5], float& bb)
{
  int g = lane / 5;
  int i = lane - g*5;
  bool okl = (lane < 15);
  int base = okl ? (g*25 + i*5) : 0;   // clamped address: safe even for inactive lanes
  int bidx = okl ? (g*5 + i) : 0;
  #pragma unroll
  for (int j=0;j<5;j++){
    float w  = W[base + j];
    float u  = U[base + j];
    float u2 = U[50 + i*5 + j];
    Wr[j]  = okl ? w : 0.0f;
    U1r[j] = (okl && g < 2) ? u  : 0.0f;
    U2r[j] = (okl && g == 2) ? u2 : 0.0f;
  }
  bb = okl ? b[bidx] : 0.0f;
}

__device__ __forceinline__ float rl(float v, int l){
  return __uint_as_float((unsigned)__builtin_amdgcn_readlane((int)__float_as_uint(v), l));
}

__device__ __forceinline__ void gru_step(const float xe[5], float s[5],
                                         const float Wr[5], const float U1r[5],
                                         const float U2r[5], float bb)
{
  float acc = bb;
  #pragma unroll
  for (int j=0;j<5;j++) acc += Wr[j]*xe[j];
  #pragma unroll
  for (int j=0;j<5;j++) acc += U1r[j]*s[j];   // U1r==0 for the c-gate lanes
  float zr = fast_sigmoid(acc);               // z on lanes 0-4, r on lanes 5-9
  float rr[5];
  #pragma unroll
  for (int j=0;j<5;j++) rr[j] = rl(zr, 5+j);
  float acc2 = acc;                           // for c-gate lanes: b2 + W2@xe
  #pragma unroll
  for (int j=0;j<5;j++) acc2 += U2r[j]*(s[j]*rr[j]);
  float cv = fast_tanh(acc2);                 // c on lanes 10-14
  #pragma unroll
  for (int j=0;j<5;j++){
    float zj = rl(zr, j);
    float cj = rl(cv, 10+j);
    s[j] = cj + zj*(s[j]-cj);                 // z*s + (1-z)*c
  }
}

// ---------- kernel A: xe_all[t,h] = sum_v x[t,v] * Eg_en[h,v] ----------
__global__ __launch_bounds__(256) void matmul_xe(const float* __restrict__ x,
                                                 const float* __restrict__ Eg_en,
                                                 float* __restrict__ xe_all)
{
  const int t = blockIdx.x;
  const int tid = threadIdx.x;
  const int lane = tid & 63, wave = tid >> 6;
  const f32x4* xr = (const f32x4*)(x + (size_t)t*VSZ);
  float acc[5] = {0,0,0,0,0};
  for (int j = tid; j < VSZ/4; j += 256){
    f32x4 xv = xr[j];
    #pragma unroll
    for (int h=0;h<5;h++){
      f32x4 ev = ((const f32x4*)(Eg_en + (size_t)h*VSZ))[j];
      acc[h] += xv.x*ev.x + xv.y*ev.y + xv.z*ev.z + xv.w*ev.w;
    }
  }
  #pragma unroll
  for (int m=1;m<64;m<<=1){
    #pragma unroll
    for (int h=0;h<5;h++) acc[h] += __shfl_xor(acc[h], m, 64);
  }
  __shared__ float part[4][5];
  if (lane == 0){
    #pragma unroll
    for (int h=0;h<5;h++) part[wave][h] = acc[h];
  }
  __syncthreads();
  if (tid < 5) xe_all[t*5 + tid] = part[0][tid] + part[1][tid] + part[2][tid] + part[3][tid];
}

// ---------- kernel B: sequential encoder scan (1 wave) + clear decoder sync slots ----------
__global__ void enc_kernel(const float* __restrict__ xe_all,
                           float* __restrict__ s_enc,
                           float* __restrict__ slots_f, // 2048 floats (8KB) to clear
                           const float* __restrict__ W, const float* __restrict__ U,
                           const float* __restrict__ b)
{
  const int lane = threadIdx.x;
  for (int k = lane; k < 2048; k += 64) slots_f[k] = 0.0f;

  float Wr[5], U1r[5], U2r[5], bb;
  load_gru_w(W, U, b, lane, Wr, U1r, U2r, bb);

  float s[5] = {0,0,0,0,0};
  float xe[5];
  #pragma unroll
  for (int j=0;j<5;j++) xe[j] = xe_all[j];
  for (int t=0; t<TT; t++){
    float nx[5];
    int tn = (t < TT-1) ? (t+1)*5 : t*5;   // prefetch next step's xe
    #pragma unroll
    for (int j=0;j<5;j++) nx[j] = xe_all[tn + j];
    gru_step(xe, s, Wr, U1r, U2r, bb);
    #pragma unroll
    for (int j=0;j<5;j++) xe[j] = nx[j];
  }
  if (lane == 0){
    #pragma unroll
    for (int j=0;j<5;j++) s_enc[j] = s[j];
  }
}

// ---------- kernel C: decoder. 16 WGs x 256 thr; weights register-resident; ----------
// ---------- 64-slot self-tagged all-to-all through L3 each step; no __syncthreads ----------
__global__ __launch_bounds__(256, 1) void dec_kernel(
    const float* __restrict__ Eg_en, const float* __restrict__ Eg_de,
    const float* __restrict__ cg_de,
    const float* __restrict__ W, const float* __restrict__ U, const float* __restrict__ b,
    const float* __restrict__ s_enc,
    unsigned long long* __restrict__ slots,   // [2 parities][64 slots][8 u64]
    float* __restrict__ out)
{
  const int wg = blockIdx.x;
  const int tid = threadIdx.x;
  const int lane = tid & 63;
  const int wave = tid >> 6;
  const int slot_id = wg*4 + wave;

  float Wr[5], U1r[5], U2r[5], bb;
  load_gru_w(W, U, b, lane, Wr, U1r, U2r, bb);

  const bool act = (tid < 250);              // 250*8 = 2000 v's per WG
  const int v0 = wg*2000 + tid*8;
  float de[8][5], en[5][8], cb[8];
  if (act){
    #pragma unroll
    for (int k=0;k<8;k++){
      #pragma unroll
      for (int j=0;j<5;j++) de[k][j] = Eg_de[(v0+k)*5 + j];
      cb[k] = cg_de[v0+k];
    }
    #pragma unroll
    for (int h=0;h<5;h++){
      #pragma unroll
      for (int k=0;k<8;k++) en[h][k] = Eg_en[h*VSZ + v0 + k];
    }
  } else {
    #pragma unroll
    for (int k=0;k<8;k++){
      cb[k] = 0.0f;
      #pragma unroll
      for (int j=0;j<5;j++) de[k][j] = 0.0f;
    }
    #pragma unroll
    for (int h=0;h<5;h++){
      #pragma unroll
      for (int k=0;k<8;k++) en[h][k] = 0.0f;
    }
  }

  float s[5];
  #pragma unroll
  for (int j=0;j<5;j++) s[j] = s_enc[j];

  for (int t=0; t<LL; t++){
    // --- u_v = relu(Eg_de[v]@s + c_v); out row t; partial xe ---
    float px[5] = {0,0,0,0,0};
    float o[8];
    #pragma unroll
    for (int k=0;k<8;k++){
      float u = cb[k];
      #pragma unroll
      for (int j=0;j<5;j++) u += de[k][j]*s[j];
      u = fmaxf(u, 0.0f);
      o[k] = u;
      #pragma unroll
      for (int h=0;h<5;h++) px[h] += u*en[h][k];
    }
    if (act){
      f32x4* po = (f32x4*)(out + (size_t)t*VSZ + v0);
      f32x4 a = {o[0], o[1], o[2], o[3]};
      f32x4 bv = {o[4], o[5], o[6], o[7]};
      po[0] = a; po[1] = bv;
    }
    if (t == LL-1) break;   // last row needs no new state

    // --- intra-wave reduce ---
    #pragma unroll
    for (int m=1;m<64;m<<=1){
      #pragma unroll
      for (int h=0;h<5;h++) px[h] += __shfl_xor(px[h], m, 64);
    }

    // --- publish: 5 self-tagged u64 words (8B atomic => no fence, no torn reads) ---
    const unsigned long long tg = (unsigned long long)(t+1);
    if (lane == 0){
      unsigned long long* wp = slots + ((size_t)(t&1)*64 + slot_id)*8;
      #pragma unroll
      for (int j=0;j<5;j++)
        __hip_atomic_store(wp+j, (tg<<32) | (unsigned long long)__float_as_uint(px[j]),
                           __ATOMIC_RELAXED, __HIP_MEMORY_SCOPE_AGENT);
    }

    // --- poll all 64 slots (lane <-> slot), parity double-buffered ---
    const unsigned long long* rp = slots + ((size_t)(t&1)*64 + lane)*8;
    unsigned long long w0,w1,w2,w3,w4;
    for(;;){
      w0 = __hip_atomic_load(rp+0, __ATOMIC_RELAXED, __HIP_MEMORY_SCOPE_AGENT);
      w1 = __hip_atomic_load(rp+1, __ATOMIC_RELAXED, __HIP_MEMORY_SCOPE_AGENT);
      w2 = __hip_atomic_load(rp+2, __ATOMIC_RELAXED, __HIP_MEMORY_SCOPE_AGENT);
      w3 = __hip_atomic_load(rp+3, __ATOMIC_RELAXED, __HIP_MEMORY_SCOPE_AGENT);
      w4 = __hip_atomic_load(rp+4, __ATOMIC_RELAXED, __HIP_MEMORY_SCOPE_AGENT);
      bool ok = ((w0>>32)==tg) & ((w1>>32)==tg) & ((w2>>32)==tg)
              & ((w3>>32)==tg) & ((w4>>32)==tg);
      if (__all(ok)) break;
    }
    float xe[5];
    xe[0] = __uint_as_float((unsigned)w0);
    xe[1] = __uint_as_float((unsigned)w1);
    xe[2] = __uint_as_float((unsigned)w2);
    xe[3] = __uint_as_float((unsigned)w3);
    xe[4] = __uint_as_float((unsigned)w4);
    #pragma unroll
    for (int m=1;m<64;m<<=1){
      #pragma unroll
      for (int j=0;j<5;j++) xe[j] += __shfl_xor(xe[j], m, 64);
    }

    // --- GRU update (redundant per wave; bitwise identical everywhere) ---
    gru_step(xe, s, Wr, U1r, U2r, bb);
  }
}

extern "C" void kernel_launch(void* const* d_in, const int* in_sizes, int n_in,
                              void* d_out, int out_size, void* d_ws, size_t ws_size,
                              hipStream_t stream)
{
  const float* x     = (const float*)d_in[0];
  // d_in[1] = l (==1024), fixed by problem shape
  const float* Eg_en = (const float*)d_in[2];
  const float* Eg_de = (const float*)d_in[3];
  const float* cg_de = (const float*)d_in[4];
  const float* Wg_en = (const float*)d_in[5];
  const float* Ug_en = (const float*)d_in[6];
  const float* bg_en = (const float*)d_in[7];
  const float* Wg_de = (const float*)d_in[8];
  const float* Ug_de = (const float*)d_in[9];
  const float* bg_de = (const float*)d_in[10];
  float* out = (float*)d_out;

  float* ws      = (float*)d_ws;
  float* xe_all  = ws;           // 1024*5 = 5120 floats
  float* s_enc   = ws + 5120;    // 5 floats (padded to 5376)
  float* slots_f = ws + 5376;    // 2048 floats = 8KB: [2][64][8] u64
  unsigned long long* slots = (unsigned long long*)slots_f;

  matmul_xe<<<dim3(TT), dim3(256), 0, stream>>>(x, Eg_en, xe_all);
  enc_kernel<<<dim3(1), dim3(64), 0, stream>>>(xe_all, s_enc, slots_f, Wg_en, Ug_en, bg_en);
  dec_kernel<<<dim3(16), dim3(256), 0, stream>>>(Eg_en, Eg_de, cg_de,
                                                 Wg_de, Ug_de, bg_de,
                                                 s_enc, slots, out);
}